// Round 9
// baseline (225.307 us; speedup 1.0000x reference)
//
#include <hip/hip_runtime.h>
#include <hip/hip_bf16.h>

// B=4, S=4096, D=1024, H=64.
// qs = LN(x@Wq), ks = LN(x@Wk), vs = x@Wv; out = softmax(qs ks^T/8) @ vs.
//  - No online softmax (LN rows have ||r||=8 -> |score|<=8); exp2 with log2e
//    folded into q's LN scale.
//  - k_attn: r7 shape (64q/block, wave=(wq,wk) 32q x 32keys, P in registers
//    via S^T C-frag == PV B-operand). r8's 128q/block REVERTED (L2 thrash:
//    WRITE_SIZE 33->114 MB). NEW: Vlds stride 70 to kill the 4-way bank
//    alias of bf16x4 V-frag reads (r7: 1.57M conflict cycles).
//  - k_proj: r6 structure + depth-2 X prefetch (X is the HBM stream, ~900cyc
//    latency >> 1-stage distance; alternate reg buffers, W depth 1 L2-hit).

typedef __bf16 bf16x8 __attribute__((ext_vector_type(8)));
typedef __bf16 bf16x4 __attribute__((ext_vector_type(4)));
typedef short s16x4 __attribute__((ext_vector_type(4)));
typedef float f32x4 __attribute__((ext_vector_type(4)));

#define NROW 16384
#define DD   1024
#define HH   64
#define SS   4096
#define LS   68     // K/X/W LDS stride (34 dw == 2 mod 32; measured 0-conflict)
#define VS   70     // V LDS stride (35 dw -> <=2-way on bf16x4 frag reads)

#if __has_builtin(__builtin_amdgcn_mfma_f32_16x16x16_bf16)
#define MFMA16(a, b, c) __builtin_amdgcn_mfma_f32_16x16x16_bf16((a), (b), (c), 0, 0, 0)
#define HAVE_MFMA16 1
#elif __has_builtin(__builtin_amdgcn_mfma_f32_16x16x16bf16_1k)
#define MFMA16(a, b, c)                                             \
  __builtin_amdgcn_mfma_f32_16x16x16bf16_1k(                        \
      __builtin_bit_cast(s16x4, (a)), __builtin_bit_cast(s16x4, (b)), (c), 0, 0, 0)
#define HAVE_MFMA16 1
#endif

static __device__ inline unsigned short f2bf_u(float x) {
  __bf16 b = (__bf16)x;
  return __builtin_bit_cast(unsigned short, b);
}
static __device__ inline uint2 pk4f(float a, float b, float c, float d) {
  return make_uint2((unsigned)f2bf_u(a) | ((unsigned)f2bf_u(b) << 16),
                    (unsigned)f2bf_u(c) | ((unsigned)f2bf_u(d) << 16));
}
static __device__ inline bf16x8 ld8(const __bf16* p) {
  bf16x4 lo = *reinterpret_cast<const bf16x4*>(p);
  bf16x4 hi = *reinterpret_cast<const bf16x4*>(p + 4);
  return __builtin_shufflevector(lo, hi, 0, 1, 2, 3, 4, 5, 6, 7);
}

// ---------------------------------------------------------------- kernel 1
__global__ __launch_bounds__(256) void k_transpose_w(
    const float* __restrict__ Wq, const float* __restrict__ Wk,
    const float* __restrict__ Wv, __bf16* __restrict__ WT) {
  int idx = blockIdx.x * 256 + threadIdx.x;   // 0..196607
  int mat = idx >> 16;
  int rem = idx & 65535;                      // k*64 + h (coalesced read)
  int k = rem >> 6, h = rem & 63;
  const float* W = (mat == 0) ? Wq : ((mat == 1) ? Wk : Wv);
  WT[(size_t)(mat * 64 + h) * DD + k] = (__bf16)W[rem];
}

// ---------------------------------------------------------------- kernel 2
// Staged projection GEMM, BK=64, 32 rows/block, 128 thr (2 waves); wave w
// owns rows 16w..16w+15 x all 12 N-tiles; LN fully in registers.
// X prefetched 2 stages ahead (alternating buffers), W 1 stage (L2-hit).
__global__ __launch_bounds__(128, 2) void k_proj(
    const float* __restrict__ X, const __bf16* __restrict__ WT,
    __bf16* __restrict__ qb, __bf16* __restrict__ kbp, __bf16* __restrict__ vT) {
  __shared__ __bf16 Xs[32 * LS];
  __shared__ __bf16 Ws[192 * LS];
  const int t = threadIdx.x, lane = t & 63, w = t >> 6;
  const int quad = lane >> 4, m = lane & 15;
  const int Mb = blockIdx.x * 32;

  f32x4 acc[12];
#pragma unroll
  for (int i = 0; i < 12; i++) acc[i] = (f32x4){0.f, 0.f, 0.f, 0.f};

  float4 xA[4], xB[4];
  bf16x8 wr[12];
#pragma unroll
  for (int i = 0; i < 4; i++) {
    int c = t + i * 128, row = c >> 4, col = (c & 15) * 4;
    xA[i] = *reinterpret_cast<const float4*>(&X[(size_t)(Mb + row) * DD + col]);
    xB[i] = *reinterpret_cast<const float4*>(&X[(size_t)(Mb + row) * DD + 64 + col]);
  }
#pragma unroll
  for (int i = 0; i < 12; i++) {
    int c = t + i * 128, row = c >> 3, col = (c & 7) * 8;
    wr[i] = *reinterpret_cast<const bf16x8*>(&WT[(size_t)row * DD + col]);
  }

  auto do_stage = [&](int s, float4* xb) {
    if (s) __syncthreads();
#pragma unroll
    for (int i = 0; i < 4; i++) {
      int c = t + i * 128, row = c >> 4, col = (c & 15) * 4;
      *reinterpret_cast<uint2*>(&Xs[row * LS + col]) =
          pk4f(xb[i].x, xb[i].y, xb[i].z, xb[i].w);
    }
#pragma unroll
    for (int i = 0; i < 12; i++) {
      int c = t + i * 128, row = c >> 3, col = (c & 7) * 8;
      uint4 raw = __builtin_bit_cast(uint4, wr[i]);
      __bf16* wd = &Ws[row * LS + col];
      *reinterpret_cast<uint2*>(wd) = make_uint2(raw.x, raw.y);
      *reinterpret_cast<uint2*>(wd + 4) = make_uint2(raw.z, raw.w);
    }
    __syncthreads();
    if (s + 1 < 16) {            // W prefetch, depth 1 (issued first)
      const int ko = (s + 1) * 64;
#pragma unroll
      for (int i = 0; i < 12; i++) {
        int c = t + i * 128, row = c >> 3, col = (c & 7) * 8;
        wr[i] = *reinterpret_cast<const bf16x8*>(
            &WT[(size_t)row * DD + ko + col]);
      }
    }
    if (s + 2 < 16) {            // X prefetch, depth 2 (reuse freed buffer)
      const int ko = (s + 2) * 64;
#pragma unroll
      for (int i = 0; i < 4; i++) {
        int c = t + i * 128, row = c >> 4, col = (c & 15) * 4;
        xb[i] = *reinterpret_cast<const float4*>(
            &X[(size_t)(Mb + row) * DD + ko + col]);
      }
    }
#pragma unroll
    for (int kk = 0; kk < 2; kk++) {
      bf16x8 a = ld8(&Xs[(16 * w + m) * LS + 32 * kk + quad * 8]);
#pragma unroll
      for (int nt = 0; nt < 12; nt++) {
        bf16x8 bfr = ld8(&Ws[(16 * nt + m) * LS + 32 * kk + quad * 8]);
        acc[nt] = __builtin_amdgcn_mfma_f32_16x16x32_bf16(a, bfr, acc[nt], 0, 0, 0);
      }
    }
  };

  for (int ss = 0; ss < 16; ss += 2) {
    do_stage(ss, xA);
    do_stage(ss + 1, xB);
  }

  // ---- fused LayerNorm in registers (r6-validated), log2e folded into q
#pragma unroll
  for (int mat = 0; mat < 2; mat++) {
#pragma unroll
    for (int reg = 0; reg < 4; reg++) {
      float s = 0.f, s2 = 0.f;
#pragma unroll
      for (int ntl = 0; ntl < 4; ntl++) {
        float x = acc[mat * 4 + ntl][reg];
        s += x; s2 += x * x;
      }
#pragma unroll
      for (int off = 1; off < 16; off <<= 1) {
        s += __shfl_xor(s, off, 64);
        s2 += __shfl_xor(s2, off, 64);
      }
      float mu = s * (1.0f / 64.0f);
      float var = s2 * (1.0f / 64.0f) - mu * mu;
      float rstd = rsqrtf(var + 1e-5f);
      float scl = (mat == 0) ? 0.125f * 1.44269504f * rstd : rstd;
#pragma unroll
      for (int ntl = 0; ntl < 4; ntl++)
        acc[mat * 4 + ntl][reg] = (acc[mat * 4 + ntl][reg] - mu) * scl;
    }
  }

  const int rowbase = Mb + 16 * w + quad * 4;
#pragma unroll
  for (int nt = 0; nt < 4; nt++)
#pragma unroll
    for (int reg = 0; reg < 4; reg++) {
      qb[(size_t)(rowbase + reg) * HH + m + 16 * nt] = (__bf16)acc[nt][reg];
      kbp[(size_t)(rowbase + reg) * HH + m + 16 * nt] = (__bf16)acc[4 + nt][reg];
    }
  const int b = Mb >> 12;
  const int s0 = (Mb & 4095) + 16 * w + quad * 4;
#pragma unroll
  for (int nt = 0; nt < 4; nt++) {
    ushort4 pk = make_ushort4(f2bf_u(acc[8 + nt][0]), f2bf_u(acc[8 + nt][1]),
                              f2bf_u(acc[8 + nt][2]), f2bf_u(acc[8 + nt][3]));
    *reinterpret_cast<ushort4*>(
        &vT[((size_t)(b * 64) + m + 16 * nt) * SS + s0]) = pk;
  }
}

// ---------------------------------------------------------------- kernel 3
// S^T attention (r7-validated). Block = 64 q x KV-split; wave (wq,wk) owns
// q-tiles {2wq,2wq+1} x key-subtiles {2wk,2wk+1}. P stays in registers.
// Vlds stride VS=70 (conflict fix). O reduced across wk via LDS once.
__global__ __launch_bounds__(256, 4) void k_attn(
    const __bf16* __restrict__ qb, const __bf16* __restrict__ kbp,
    const __bf16* __restrict__ vT, float* __restrict__ Op,
    float* __restrict__ lp, int spbits) {
  __shared__ __align__(16) char smem[17664];
  __bf16* Klds = (__bf16*)smem;              // [64 keys][h], stride LS (8704B)
  __bf16* Vlds = (__bf16*)(smem + 8704);     // [64 h][key], stride VS (8960B)
  const int t = threadIdx.x, lane = t & 63, w = t >> 6;
  const int quad = lane >> 4, m = lane & 15;
  const int wq = w >> 1, wk = w & 1;
  const int nsp = 1 << spbits;
  const int qt = blockIdx.x >> spbits, sp = blockIdx.x & (nsp - 1);
  const int KPS = SS >> spbits;
  const int Mb = qt * 64;
  const int b = Mb >> 12;
  const size_t kvbase = (size_t)b * SS * HH;

  // Q fragments (B-operand): [ntl][kk]
  bf16x8 qf[2][2];
#pragma unroll
  for (int ntl = 0; ntl < 2; ntl++)
#pragma unroll
    for (int kk = 0; kk < 2; kk++)
      qf[ntl][kk] = *reinterpret_cast<const bf16x8*>(
          &qb[(size_t)(Mb + (2 * wq + ntl) * 16 + m) * HH + 32 * kk + quad * 8]);

  f32x4 O[4][2];   // [ht][ntl]
#pragma unroll
  for (int i = 0; i < 4; i++)
#pragma unroll
    for (int j = 0; j < 2; j++) O[i][j] = (f32x4){0.f, 0.f, 0.f, 0.f};
  float ll[2] = {0.f, 0.f};

  const int c0row = t >> 3, ck0 = (t & 7) * 8;
  const int c1row = c0row + 32;
  const int kb_lo = sp * KPS, kb_hi = kb_lo + KPS;

  uint4 kd0, kd1, vd0, vd1;
  kd0 = *reinterpret_cast<const uint4*>(&kbp[kvbase + (size_t)(kb_lo + c0row) * HH + ck0]);
  kd1 = *reinterpret_cast<const uint4*>(&kbp[kvbase + (size_t)(kb_lo + c1row) * HH + ck0]);
  vd0 = *reinterpret_cast<const uint4*>(&vT[(size_t)(b * 64 + c0row) * SS + kb_lo + ck0]);
  vd1 = *reinterpret_cast<const uint4*>(&vT[(size_t)(b * 64 + c1row) * SS + kb_lo + ck0]);

  for (int kb0 = kb_lo; kb0 < kb_hi; kb0 += 64) {
    {
      __bf16* kp0 = &Klds[c0row * LS + ck0];
      __bf16* kp1 = &Klds[c1row * LS + ck0];
      __bf16* vp0 = &Vlds[c0row * VS + ck0];
      __bf16* vp1 = &Vlds[c1row * VS + ck0];
      *reinterpret_cast<uint2*>(kp0) = make_uint2(kd0.x, kd0.y);
      *reinterpret_cast<uint2*>(kp0 + 4) = make_uint2(kd0.z, kd0.w);
      *reinterpret_cast<uint2*>(kp1) = make_uint2(kd1.x, kd1.y);
      *reinterpret_cast<uint2*>(kp1 + 4) = make_uint2(kd1.z, kd1.w);
      *reinterpret_cast<uint2*>(vp0) = make_uint2(vd0.x, vd0.y);
      *reinterpret_cast<uint2*>(vp0 + 4) = make_uint2(vd0.z, vd0.w);
      *reinterpret_cast<uint2*>(vp1) = make_uint2(vd1.x, vd1.y);
      *reinterpret_cast<uint2*>(vp1 + 4) = make_uint2(vd1.z, vd1.w);
    }
    __syncthreads();
    if (kb0 + 64 < kb_hi) {
      kd0 = *reinterpret_cast<const uint4*>(&kbp[kvbase + (size_t)(kb0 + 64 + c0row) * HH + ck0]);
      kd1 = *reinterpret_cast<const uint4*>(&kbp[kvbase + (size_t)(kb0 + 64 + c1row) * HH + ck0]);
      vd0 = *reinterpret_cast<const uint4*>(&vT[(size_t)(b * 64 + c0row) * SS + kb0 + 64 + ck0]);
      vd1 = *reinterpret_cast<const uint4*>(&vT[(size_t)(b * 64 + c1row) * SS + kb0 + 64 + ck0]);
    }

#pragma unroll
    for (int ktl = 0; ktl < 2; ktl++) {
      const int kt = 2 * wk + ktl;
      // S^T = K Q^T : A = K rows (keys as M), B = Q regs
      f32x4 sc[2];
      sc[0] = (f32x4){0.f, 0.f, 0.f, 0.f};
      sc[1] = (f32x4){0.f, 0.f, 0.f, 0.f};
#pragma unroll
      for (int kk = 0; kk < 2; kk++) {
        bf16x8 kf = ld8(&Klds[(kt * 16 + m) * LS + 32 * kk + quad * 8]);
        sc[0] = __builtin_amdgcn_mfma_f32_16x16x32_bf16(kf, qf[0][kk], sc[0], 0, 0, 0);
        sc[1] = __builtin_amdgcn_mfma_f32_16x16x32_bf16(kf, qf[1][kk], sc[1], 0, 0, 0);
      }
#pragma unroll
      for (int ntl = 0; ntl < 2; ntl++) {
        float p0 = exp2f(sc[ntl][0]), p1 = exp2f(sc[ntl][1]);
        float p2 = exp2f(sc[ntl][2]), p3 = exp2f(sc[ntl][3]);
        ll[ntl] += (p0 + p1) + (p2 + p3);
        bf16x4 pf;
        pf[0] = (__bf16)p0; pf[1] = (__bf16)p1;
        pf[2] = (__bf16)p2; pf[3] = (__bf16)p3;
#ifdef HAVE_MFMA16
#pragma unroll
        for (int ht = 0; ht < 4; ht++) {
          bf16x4 vf = *reinterpret_cast<const bf16x4*>(
              &Vlds[(16 * ht + m) * VS + kt * 16 + quad * 4]);
          O[ht][ntl] = MFMA16(vf, pf, O[ht][ntl]);
        }
#else
        uint2 pd = __builtin_bit_cast(uint2, pf);
        int lo_src = 32 * quad + m, hi_src = 32 * quad + 16 + m;
        unsigned b0 = (unsigned)__shfl((int)pd.x, lo_src, 64);
        unsigned b1 = (unsigned)__shfl((int)pd.y, lo_src, 64);
        unsigned b2 = (unsigned)__shfl((int)pd.x, hi_src, 64);
        unsigned b3 = (unsigned)__shfl((int)pd.y, hi_src, 64);
        uint4 bz = (quad < 2) ? make_uint4(b0, b1, b2, b3)
                              : make_uint4(0u, 0u, 0u, 0u);
        bf16x8 bfrag = __builtin_bit_cast(bf16x8, bz);
#pragma unroll
        for (int ht = 0; ht < 4; ht++) {
          bf16x8 vf = ld8(&Vlds[(16 * ht + m) * VS + kt * 16 + (quad & 1) * 8]);
          O[ht][ntl] =
              __builtin_amdgcn_mfma_f32_16x16x32_bf16(vf, bfrag, O[ht][ntl], 0, 0, 0);
        }
#endif
      }
    }
    __syncthreads();
  }

  // l: sum over quads (keys quad*4+reg within the wave's subtiles)
#pragma unroll
  for (int ntl = 0; ntl < 2; ntl++) {
    ll[ntl] += __shfl_xor(ll[ntl], 16, 64);
    ll[ntl] += __shfl_xor(ll[ntl], 32, 64);
  }

  // ---- cross-wk reduce via LDS (union over K/V buffers), then store
  float* obuf = (float*)smem;            // [wq][64 h][stride 33]
  float* lbuf = (float*)(smem + 16896);  // 64 floats
  __syncthreads();
  if (wk == 1) {
#pragma unroll
    for (int ht = 0; ht < 4; ht++)
#pragma unroll
      for (int ntl = 0; ntl < 2; ntl++)
#pragma unroll
        for (int reg = 0; reg < 4; reg++)
          obuf[wq * 2112 + (16 * ht + quad * 4 + reg) * 33 + ntl * 16 + m] =
              O[ht][ntl][reg];
    if (quad == 0) {
      lbuf[(2 * wq + 0) * 16 + m] = ll[0];
      lbuf[(2 * wq + 1) * 16 + m] = ll[1];
    }
  }
  __syncthreads();
  if (wk == 0) {
#pragma unroll
    for (int ht = 0; ht < 4; ht++)
#pragma unroll
      for (int ntl = 0; ntl < 2; ntl++)
#pragma unroll
        for (int reg = 0; reg < 4; reg++)
          O[ht][ntl][reg] +=
              obuf[wq * 2112 + (16 * ht + quad * 4 + reg) * 33 + ntl * 16 + m];
#pragma unroll
    for (int ntl = 0; ntl < 2; ntl++) {
      const int qg = Mb + (2 * wq + ntl) * 16 + m;
      ll[ntl] += lbuf[(2 * wq + ntl) * 16 + m];
#pragma unroll
      for (int ht = 0; ht < 4; ht++) {
        f32x4 v = O[ht][ntl];
        *reinterpret_cast<float4*>(
            &Op[((size_t)sp * NROW + qg) * HH + 16 * ht + 4 * quad]) =
            make_float4(v[0], v[1], v[2], v[3]);
      }
      if (quad == 0) lp[sp * NROW + qg] = ll[ntl];
    }
  }
}

// ---------------------------------------------------------------- kernel 4
__global__ __launch_bounds__(256) void k_comb(const float* __restrict__ Op,
                                              const float* __restrict__ lp,
                                              float* __restrict__ out, int nsp) {
  int idx = blockIdx.x * 256 + threadIdx.x;   // < NROW*HH
  int row = idx >> 6;
  float o = 0.f, l = 0.f;
  for (int j = 0; j < nsp; j++) {
    o += Op[(size_t)j * NROW * HH + idx];
    l += lp[j * NROW + row];
  }
  out[idx] = o / l;
}

// ---------------------------------------------------------------- launch
extern "C" void kernel_launch(void* const* d_in, const int* in_sizes, int n_in,
                              void* d_out, int out_size, void* d_ws, size_t ws_size,
                              hipStream_t stream) {
  const float* X  = (const float*)d_in[0];
  const float* Wq = (const float*)d_in[1];
  const float* Wk = (const float*)d_in[2];
  const float* Wv = (const float*)d_in[3];
  float* out = (float*)d_out;
  char* ws = (char*)d_ws;

  __bf16* WT  = (__bf16*)(ws);                          // 384 KB
  __bf16* qb  = (__bf16*)(ws + (size_t)512 * 1024);     // 2 MB
  __bf16* kbp = (__bf16*)(ws + (size_t)2560 * 1024);    // 2 MB
  __bf16* vT  = (__bf16*)(ws + (size_t)4608 * 1024);    // 2 MB
  float*  Op  = (float*)(ws + (size_t)6656 * 1024);     // nsp * 4 MB
  const size_t need8 = (size_t)(6656 + 8 * 4096 + 512) * 1024;
  const int spbits = (ws_size >= need8) ? 3 : 2;
  const int nsp = 1 << spbits;
  float* lp = (float*)(ws + (size_t)(6656 + nsp * 4096) * 1024);

  hipLaunchKernelGGL(k_transpose_w, dim3(768), dim3(256), 0, stream, Wq, Wk, Wv, WT);
  hipLaunchKernelGGL(k_proj, dim3(NROW / 32), dim3(128), 0, stream, X, WT, qb, kbp, vT);
  hipLaunchKernelGGL(k_attn, dim3((NROW / 64) * nsp), dim3(256), 0, stream,
                     qb, kbp, vT, Op, lp, spbits);
  hipLaunchKernelGGL(k_comb, dim3(NROW * HH / 256), dim3(256), 0, stream,
                     Op, lp, out, nsp);
}

// Round 11
// 161.238 us; speedup vs baseline: 1.3974x; 1.3974x over previous
//
#include <hip/hip_runtime.h>
#include <hip/hip_bf16.h>

// B=4, S=4096, D=1024, H=64.
// qs = LN(x@Wq), ks = LN(x@Wk), vs = x@Wv; out = softmax(qs ks^T/8) @ vs.
//  - No online softmax (LN rows have ||r||=8 -> |score|<=8); exp2 with log2e
//    folded into q's LN scale.
//  - k_attn: byte-exact r7 (best measured 41.5us). Stride-70 alignment
//    disaster (r9) and 128q/block L2 thrash (r8) both REVERTED. LDS stride
//    68 everywhere: 8B-aligned rows, measured-benign conflicts.
//  - k_proj: r6 structure with BK=128 (8 stages, half the barriers; kernel
//    is barrier-serialization-bound, LDS-pipe floor ~13us vs measured ~37).
//  - nsp=4: Op traffic halved vs nsp=8 (attn dur was nsp-insensitive r2/r6).
// (Resubmission of round-10 kernel: bench never ran — GPU acquisition
//  timeout, no measurement to learn from.)

typedef __bf16 bf16x8 __attribute__((ext_vector_type(8)));
typedef __bf16 bf16x4 __attribute__((ext_vector_type(4)));
typedef short s16x4 __attribute__((ext_vector_type(4)));
typedef float f32x4 __attribute__((ext_vector_type(4)));

#define NROW 16384
#define DD   1024
#define HH   64
#define SS   4096
#define LS   68     // k_attn LDS stride (34 dw == 2 mod 32; 8B-aligned rows)
#define LSP  132    // k_proj BK=128 stride (66 dw == 2 mod 32; 8B-aligned)

#if __has_builtin(__builtin_amdgcn_mfma_f32_16x16x16_bf16)
#define MFMA16(a, b, c) __builtin_amdgcn_mfma_f32_16x16x16_bf16((a), (b), (c), 0, 0, 0)
#define HAVE_MFMA16 1
#elif __has_builtin(__builtin_amdgcn_mfma_f32_16x16x16bf16_1k)
#define MFMA16(a, b, c)                                             \
  __builtin_amdgcn_mfma_f32_16x16x16bf16_1k(                        \
      __builtin_bit_cast(s16x4, (a)), __builtin_bit_cast(s16x4, (b)), (c), 0, 0, 0)
#define HAVE_MFMA16 1
#endif

static __device__ inline unsigned short f2bf_u(float x) {
  __bf16 b = (__bf16)x;
  return __builtin_bit_cast(unsigned short, b);
}
static __device__ inline uint2 pk4f(float a, float b, float c, float d) {
  return make_uint2((unsigned)f2bf_u(a) | ((unsigned)f2bf_u(b) << 16),
                    (unsigned)f2bf_u(c) | ((unsigned)f2bf_u(d) << 16));
}
static __device__ inline bf16x8 ld8(const __bf16* p) {
  bf16x4 lo = *reinterpret_cast<const bf16x4*>(p);
  bf16x4 hi = *reinterpret_cast<const bf16x4*>(p + 4);
  return __builtin_shufflevector(lo, hi, 0, 1, 2, 3, 4, 5, 6, 7);
}

// ---------------------------------------------------------------- kernel 1
__global__ __launch_bounds__(256) void k_transpose_w(
    const float* __restrict__ Wq, const float* __restrict__ Wk,
    const float* __restrict__ Wv, __bf16* __restrict__ WT) {
  int idx = blockIdx.x * 256 + threadIdx.x;   // 0..196607
  int mat = idx >> 16;
  int rem = idx & 65535;                      // k*64 + h (coalesced read)
  int k = rem >> 6, h = rem & 63;
  const float* W = (mat == 0) ? Wq : ((mat == 1) ? Wk : Wv);
  WT[(size_t)(mat * 64 + h) * DD + k] = (__bf16)W[rem];
}

// ---------------------------------------------------------------- kernel 2
// Staged projection GEMM, BK=128 (8 stages), 32 rows/block, 128 thr
// (2 waves); wave w owns rows 16w..16w+15 x all 12 N-tiles; LN in registers.
__global__ __launch_bounds__(128, 2) void k_proj(
    const float* __restrict__ X, const __bf16* __restrict__ WT,
    __bf16* __restrict__ qb, __bf16* __restrict__ kbp, __bf16* __restrict__ vT) {
  __shared__ __bf16 Xs[32 * LSP];    // 8448 B
  __shared__ __bf16 Ws[192 * LSP];   // 50688 B
  const int t = threadIdx.x, lane = t & 63, w = t >> 6;
  const int quad = lane >> 4, m = lane & 15;
  const int Mb = blockIdx.x * 32;

  f32x4 acc[12];
#pragma unroll
  for (int i = 0; i < 12; i++) acc[i] = (f32x4){0.f, 0.f, 0.f, 0.f};

  // staging maps (fully coalesced):
  //  X: 1024 float4 chunks; c = t + 128i (i<8): row=c>>5, col=(c&31)*4
  //  W: 3072 bf16x8 chunks; c = t + 128i (i<24): row=c>>4, col=(c&15)*8
  float4 xr[8];
  bf16x8 wr[24];
#pragma unroll
  for (int i = 0; i < 8; i++) {
    int c = t + i * 128, row = c >> 5, col = (c & 31) * 4;
    xr[i] = *reinterpret_cast<const float4*>(&X[(size_t)(Mb + row) * DD + col]);
  }
#pragma unroll
  for (int i = 0; i < 24; i++) {
    int c = t + i * 128, row = c >> 4, col = (c & 15) * 8;
    wr[i] = *reinterpret_cast<const bf16x8*>(&WT[(size_t)row * DD + col]);
  }

  for (int s = 0; s < 8; s++) {
    if (s) __syncthreads();               // prev compute done, LDS writable
#pragma unroll
    for (int i = 0; i < 8; i++) {
      int c = t + i * 128, row = c >> 5, col = (c & 31) * 4;
      *reinterpret_cast<uint2*>(&Xs[row * LSP + col]) =
          pk4f(xr[i].x, xr[i].y, xr[i].z, xr[i].w);
    }
#pragma unroll
    for (int i = 0; i < 24; i++) {
      int c = t + i * 128, row = c >> 4, col = (c & 15) * 8;
      uint4 raw = __builtin_bit_cast(uint4, wr[i]);
      __bf16* wd = &Ws[row * LSP + col];
      *reinterpret_cast<uint2*>(wd) = make_uint2(raw.x, raw.y);
      *reinterpret_cast<uint2*>(wd + 4) = make_uint2(raw.z, raw.w);
    }
    __syncthreads();                      // LDS ready
    if (s + 1 < 8) {                      // prefetch next stage into regs
      const int ko = (s + 1) * 128;
#pragma unroll
      for (int i = 0; i < 8; i++) {
        int c = t + i * 128, row = c >> 5, col = (c & 31) * 4;
        xr[i] = *reinterpret_cast<const float4*>(
            &X[(size_t)(Mb + row) * DD + ko + col]);
      }
#pragma unroll
      for (int i = 0; i < 24; i++) {
        int c = t + i * 128, row = c >> 4, col = (c & 15) * 8;
        wr[i] = *reinterpret_cast<const bf16x8*>(
            &WT[(size_t)row * DD + ko + col]);
      }
    }
#pragma unroll
    for (int kk = 0; kk < 4; kk++) {
      bf16x8 a = ld8(&Xs[(16 * w + m) * LSP + 32 * kk + quad * 8]);
#pragma unroll
      for (int nt = 0; nt < 12; nt++) {
        bf16x8 bfr = ld8(&Ws[(16 * nt + m) * LSP + 32 * kk + quad * 8]);
        acc[nt] = __builtin_amdgcn_mfma_f32_16x16x32_bf16(a, bfr, acc[nt], 0, 0, 0);
      }
    }
  }

  // ---- fused LayerNorm in registers (r6-validated), log2e folded into q
#pragma unroll
  for (int mat = 0; mat < 2; mat++) {
#pragma unroll
    for (int reg = 0; reg < 4; reg++) {
      float s = 0.f, s2 = 0.f;
#pragma unroll
      for (int ntl = 0; ntl < 4; ntl++) {
        float x = acc[mat * 4 + ntl][reg];
        s += x; s2 += x * x;
      }
#pragma unroll
      for (int off = 1; off < 16; off <<= 1) {
        s += __shfl_xor(s, off, 64);
        s2 += __shfl_xor(s2, off, 64);
      }
      float mu = s * (1.0f / 64.0f);
      float var = s2 * (1.0f / 64.0f) - mu * mu;
      float rstd = rsqrtf(var + 1e-5f);
      float scl = (mat == 0) ? 0.125f * 1.44269504f * rstd : rstd;
#pragma unroll
      for (int ntl = 0; ntl < 4; ntl++)
        acc[mat * 4 + ntl][reg] = (acc[mat * 4 + ntl][reg] - mu) * scl;
    }
  }

  const int rowbase = Mb + 16 * w + quad * 4;
#pragma unroll
  for (int nt = 0; nt < 4; nt++)
#pragma unroll
    for (int reg = 0; reg < 4; reg++) {
      qb[(size_t)(rowbase + reg) * HH + m + 16 * nt] = (__bf16)acc[nt][reg];
      kbp[(size_t)(rowbase + reg) * HH + m + 16 * nt] = (__bf16)acc[4 + nt][reg];
    }
  const int b = Mb >> 12;
  const int s0 = (Mb & 4095) + 16 * w + quad * 4;
#pragma unroll
  for (int nt = 0; nt < 4; nt++) {
    ushort4 pk = make_ushort4(f2bf_u(acc[8 + nt][0]), f2bf_u(acc[8 + nt][1]),
                              f2bf_u(acc[8 + nt][2]), f2bf_u(acc[8 + nt][3]));
    *reinterpret_cast<ushort4*>(
        &vT[((size_t)(b * 64) + m + 16 * nt) * SS + s0]) = pk;
  }
}

// ---------------------------------------------------------------- kernel 3
// S^T attention (r7 byte-exact). Block = 64 q x KV-split; wave (wq,wk) owns
// q-tiles {2wq,2wq+1} x key-subtiles {2wk,2wk+1}. P stays in registers
// (S^T C-frag == PV B-operand). O reduced across wk via LDS once.
__global__ __launch_bounds__(256, 4) void k_attn(
    const __bf16* __restrict__ qb, const __bf16* __restrict__ kbp,
    const __bf16* __restrict__ vT, float* __restrict__ Op,
    float* __restrict__ lp, int spbits) {
  __shared__ __align__(16) char smem[17408];
  __bf16* Klds = (__bf16*)smem;              // [64 keys][h], stride LS
  __bf16* Vlds = (__bf16*)(smem + 8704);     // [64 h][key], stride LS
  const int t = threadIdx.x, lane = t & 63, w = t >> 6;
  const int quad = lane >> 4, m = lane & 15;
  const int wq = w >> 1, wk = w & 1;
  const int nsp = 1 << spbits;
  const int qt = blockIdx.x >> spbits, sp = blockIdx.x & (nsp - 1);
  const int KPS = SS >> spbits;
  const int Mb = qt * 64;
  const int b = Mb >> 12;
  const size_t kvbase = (size_t)b * SS * HH;

  // Q fragments (B-operand): [ntl][kk]
  bf16x8 qf[2][2];
#pragma unroll
  for (int ntl = 0; ntl < 2; ntl++)
#pragma unroll
    for (int kk = 0; kk < 2; kk++)
      qf[ntl][kk] = *reinterpret_cast<const bf16x8*>(
          &qb[(size_t)(Mb + (2 * wq + ntl) * 16 + m) * HH + 32 * kk + quad * 8]);

  f32x4 O[4][2];   // [ht][ntl]
#pragma unroll
  for (int i = 0; i < 4; i++)
#pragma unroll
    for (int j = 0; j < 2; j++) O[i][j] = (f32x4){0.f, 0.f, 0.f, 0.f};
  float ll[2] = {0.f, 0.f};

  const int c0row = t >> 3, ck0 = (t & 7) * 8;
  const int c1row = c0row + 32;
  const int kb_lo = sp * KPS, kb_hi = kb_lo + KPS;

  uint4 kd0, kd1, vd0, vd1;
  kd0 = *reinterpret_cast<const uint4*>(&kbp[kvbase + (size_t)(kb_lo + c0row) * HH + ck0]);
  kd1 = *reinterpret_cast<const uint4*>(&kbp[kvbase + (size_t)(kb_lo + c1row) * HH + ck0]);
  vd0 = *reinterpret_cast<const uint4*>(&vT[(size_t)(b * 64 + c0row) * SS + kb_lo + ck0]);
  vd1 = *reinterpret_cast<const uint4*>(&vT[(size_t)(b * 64 + c1row) * SS + kb_lo + ck0]);

  for (int kb0 = kb_lo; kb0 < kb_hi; kb0 += 64) {
    {
      __bf16* kp0 = &Klds[c0row * LS + ck0];
      __bf16* kp1 = &Klds[c1row * LS + ck0];
      __bf16* vp0 = &Vlds[c0row * LS + ck0];
      __bf16* vp1 = &Vlds[c1row * LS + ck0];
      *reinterpret_cast<uint2*>(kp0) = make_uint2(kd0.x, kd0.y);
      *reinterpret_cast<uint2*>(kp0 + 4) = make_uint2(kd0.z, kd0.w);
      *reinterpret_cast<uint2*>(kp1) = make_uint2(kd1.x, kd1.y);
      *reinterpret_cast<uint2*>(kp1 + 4) = make_uint2(kd1.z, kd1.w);
      *reinterpret_cast<uint2*>(vp0) = make_uint2(vd0.x, vd0.y);
      *reinterpret_cast<uint2*>(vp0 + 4) = make_uint2(vd0.z, vd0.w);
      *reinterpret_cast<uint2*>(vp1) = make_uint2(vd1.x, vd1.y);
      *reinterpret_cast<uint2*>(vp1 + 4) = make_uint2(vd1.z, vd1.w);
    }
    __syncthreads();
    if (kb0 + 64 < kb_hi) {
      kd0 = *reinterpret_cast<const uint4*>(&kbp[kvbase + (size_t)(kb0 + 64 + c0row) * HH + ck0]);
      kd1 = *reinterpret_cast<const uint4*>(&kbp[kvbase + (size_t)(kb0 + 64 + c1row) * HH + ck0]);
      vd0 = *reinterpret_cast<const uint4*>(&vT[(size_t)(b * 64 + c0row) * SS + kb0 + 64 + ck0]);
      vd1 = *reinterpret_cast<const uint4*>(&vT[(size_t)(b * 64 + c1row) * SS + kb0 + 64 + ck0]);
    }

#pragma unroll
    for (int ktl = 0; ktl < 2; ktl++) {
      const int kt = 2 * wk + ktl;
      // S^T = K Q^T : A = K rows (keys as M), B = Q regs
      f32x4 sc[2];
      sc[0] = (f32x4){0.f, 0.f, 0.f, 0.f};
      sc[1] = (f32x4){0.f, 0.f, 0.f, 0.f};
#pragma unroll
      for (int kk = 0; kk < 2; kk++) {
        bf16x8 kf = ld8(&Klds[(kt * 16 + m) * LS + 32 * kk + quad * 8]);
        sc[0] = __builtin_amdgcn_mfma_f32_16x16x32_bf16(kf, qf[0][kk], sc[0], 0, 0, 0);
        sc[1] = __builtin_amdgcn_mfma_f32_16x16x32_bf16(kf, qf[1][kk], sc[1], 0, 0, 0);
      }
#pragma unroll
      for (int ntl = 0; ntl < 2; ntl++) {
        float p0 = exp2f(sc[ntl][0]), p1 = exp2f(sc[ntl][1]);
        float p2 = exp2f(sc[ntl][2]), p3 = exp2f(sc[ntl][3]);
        ll[ntl] += (p0 + p1) + (p2 + p3);
        bf16x4 pf;
        pf[0] = (__bf16)p0; pf[1] = (__bf16)p1;
        pf[2] = (__bf16)p2; pf[3] = (__bf16)p3;
#ifdef HAVE_MFMA16
#pragma unroll
        for (int ht = 0; ht < 4; ht++) {
          bf16x4 vf = *reinterpret_cast<const bf16x4*>(
              &Vlds[(16 * ht + m) * LS + kt * 16 + quad * 4]);
          O[ht][ntl] = MFMA16(vf, pf, O[ht][ntl]);
        }
#else
        uint2 pd = __builtin_bit_cast(uint2, pf);
        int lo_src = 32 * quad + m, hi_src = 32 * quad + 16 + m;
        unsigned b0 = (unsigned)__shfl((int)pd.x, lo_src, 64);
        unsigned b1 = (unsigned)__shfl((int)pd.y, lo_src, 64);
        unsigned b2 = (unsigned)__shfl((int)pd.x, hi_src, 64);
        unsigned b3 = (unsigned)__shfl((int)pd.y, hi_src, 64);
        uint4 bz = (quad < 2) ? make_uint4(b0, b1, b2, b3)
                              : make_uint4(0u, 0u, 0u, 0u);
        bf16x8 bfrag = __builtin_bit_cast(bf16x8, bz);
#pragma unroll
        for (int ht = 0; ht < 4; ht++) {
          bf16x8 vf = ld8(&Vlds[(16 * ht + m) * LS + kt * 16 + (quad & 1) * 8]);
          O[ht][ntl] =
              __builtin_amdgcn_mfma_f32_16x16x32_bf16(vf, bfrag, O[ht][ntl], 0, 0, 0);
        }
#endif
      }
    }
    __syncthreads();
  }

  // l: sum over quads (keys quad*4+reg within the wave's subtiles)
#pragma unroll
  for (int ntl = 0; ntl < 2; ntl++) {
    ll[ntl] += __shfl_xor(ll[ntl], 16, 64);
    ll[ntl] += __shfl_xor(ll[ntl], 32, 64);
  }

  // ---- cross-wk reduce via LDS (union over K/V buffers), then store
  float* obuf = (float*)smem;            // [wq][64 h][stride 33]
  float* lbuf = (float*)(smem + 16896);  // 64 floats
  __syncthreads();
  if (wk == 1) {
#pragma unroll
    for (int ht = 0; ht < 4; ht++)
#pragma unroll
      for (int ntl = 0; ntl < 2; ntl++)
#pragma unroll
        for (int reg = 0; reg < 4; reg++)
          obuf[wq * 2112 + (16 * ht + quad * 4 + reg) * 33 + ntl * 16 + m] =
              O[ht][ntl][reg];
    if (quad == 0) {
      lbuf[(2 * wq + 0) * 16 + m] = ll[0];
      lbuf[(2 * wq + 1) * 16 + m] = ll[1];
    }
  }
  __syncthreads();
  if (wk == 0) {
#pragma unroll
    for (int ht = 0; ht < 4; ht++)
#pragma unroll
      for (int ntl = 0; ntl < 2; ntl++)
#pragma unroll
        for (int reg = 0; reg < 4; reg++)
          O[ht][ntl][reg] +=
              obuf[wq * 2112 + (16 * ht + quad * 4 + reg) * 33 + ntl * 16 + m];
#pragma unroll
    for (int ntl = 0; ntl < 2; ntl++) {
      const int qg = Mb + (2 * wq + ntl) * 16 + m;
      ll[ntl] += lbuf[(2 * wq + ntl) * 16 + m];
#pragma unroll
      for (int ht = 0; ht < 4; ht++) {
        f32x4 v = O[ht][ntl];
        *reinterpret_cast<float4*>(
            &Op[((size_t)sp * NROW + qg) * HH + 16 * ht + 4 * quad]) =
            make_float4(v[0], v[1], v[2], v[3]);
      }
      if (quad == 0) lp[sp * NROW + qg] = ll[ntl];
    }
  }
}

// ---------------------------------------------------------------- kernel 4
// Op is [sp][q][h] (true h) -> fully coalesced reads and writes.
__global__ __launch_bounds__(256) void k_comb(const float* __restrict__ Op,
                                              const float* __restrict__ lp,
                                              float* __restrict__ out, int nsp) {
  int idx = blockIdx.x * 256 + threadIdx.x;   // < NROW*HH
  int row = idx >> 6;
  float o = 0.f, l = 0.f;
  for (int j = 0; j < nsp; j++) {
    o += Op[(size_t)j * NROW * HH + idx];
    l += lp[j * NROW + row];
  }
  out[idx] = o / l;
}

// ---------------------------------------------------------------- launch
extern "C" void kernel_launch(void* const* d_in, const int* in_sizes, int n_in,
                              void* d_out, int out_size, void* d_ws, size_t ws_size,
                              hipStream_t stream) {
  const float* X  = (const float*)d_in[0];
  const float* Wq = (const float*)d_in[1];
  const float* Wk = (const float*)d_in[2];
  const float* Wv = (const float*)d_in[3];
  float* out = (float*)d_out;
  char* ws = (char*)d_ws;

  __bf16* WT  = (__bf16*)(ws);                          // 384 KB
  __bf16* qb  = (__bf16*)(ws + (size_t)512 * 1024);     // 2 MB
  __bf16* kbp = (__bf16*)(ws + (size_t)2560 * 1024);    // 2 MB
  __bf16* vT  = (__bf16*)(ws + (size_t)4608 * 1024);    // 2 MB
  float*  Op  = (float*)(ws + (size_t)6656 * 1024);     // nsp * 4 MB
  const int spbits = 2;                                  // nsp=4 (Op 16 MB)
  const int nsp = 1 << spbits;
  float* lp = (float*)(ws + (size_t)(6656 + nsp * 4096) * 1024);

  hipLaunchKernelGGL(k_transpose_w, dim3(768), dim3(256), 0, stream, Wq, Wk, Wv, WT);
  hipLaunchKernelGGL(k_proj, dim3(NROW / 32), dim3(128), 0, stream, X, WT, qb, kbp, vT);
  hipLaunchKernelGGL(k_attn, dim3((NROW / 64) * nsp), dim3(256), 0, stream,
                     qb, kbp, vT, Op, lp, spbits);
  hipLaunchKernelGGL(k_comb, dim3(NROW * HH / 256), dim3(256), 0, stream,
                     Op, lp, out, nsp);
}